// Round 1
// baseline (107.532 us; speedup 1.0000x reference)
//
#include <hip/hip_runtime.h>

// ConvCaps EM routing, MI355X.
// Geometry: b=16, H=W=14, B_IN=32, P=4 (PSIZE=16), K=3, stride=2 -> oh=ow=6.
// N = K*K*B_IN = 288 input capsules per position, C_OUT = 32, ITERS = 3.
// One block per output position (576 blocks), 256 threads (4 waves).
// Per step each half-wave owns one n; lane&31 = output capsule c; lane holds all 16 il.

#define NB 288
#define NSTEP 36          // per-wave n steps: 4 waves * 36 steps * 2 halves = 288
#define LN2PI 1.8378770664093453f

__global__ __launch_bounds__(256, 2)
void convcaps_em(const float* __restrict__ x,
                 const float* __restrict__ a,
                 const float* __restrict__ W,
                 const float* __restrict__ bu,
                 const float* __restrict__ ba,
                 float* __restrict__ out)
{
    __shared__ __align__(16) float pose_s[NB * 16];   // 18432 B
    __shared__ __align__(16) float ain_s[NB];         //  1152 B
    __shared__ __align__(16) float S1w[4][32][16];    //  8192 B
    __shared__ __align__(16) float S2w[4][32][16];    //  8192 B
    __shared__             float Rw[4][32];           //   512 B
    __shared__ __align__(16) float mu_s[32][16];      //  2048 B
    __shared__ __align__(16) float p_s[32][16];       //  2048 B
    __shared__             float A_s[32];             //   128 B

    const int tid  = threadIdx.x;
    const int wv   = tid >> 6;          // wave 0..3
    const int lane = tid & 63;
    const int half = (lane >> 5) & 1;   // which n of the pair
    const int c    = lane & 31;         // output capsule

    const int bid = blockIdx.x;         // b*36 + oy*6 + ox
    const int b   = bid / 36;
    const int rem = bid % 36;
    const int oy  = rem / 6, ox = rem % 6;
    const int iy0 = oy * 2, ix0 = ox * 2;

    // ---- stage pose patch (9 x 512 floats) and a patch (9 x 32 floats) into LDS ----
    {
        const float4* x4 = (const float4*)x;
        float4* d4 = (float4*)pose_s;
        #pragma unroll
        for (int i = 0; i < 5; ++i) {
            int idx = tid + i * 256;
            if (idx < 1152) {                       // 9 segs * 128 float4
                int seg = idx >> 7, u = idx & 127;
                int kh = seg / 3, kw = seg % 3;
                d4[idx] = x4[((b * 14 + iy0 + kh) * 14 + (ix0 + kw)) * 128 + u];
            }
        }
        const float4* a4 = (const float4*)a;
        float4* e4 = (float4*)ain_s;
        if (tid < 72) {                             // 9 segs * 8 float4
            int seg = tid >> 3, u = tid & 7;
            int kh = seg / 3, kw = seg % 3;
            e4[tid] = a4[((b * 14 + iy0 + kh) * 14 + (ix0 + kw)) * 8 + u];
        }
    }
    __syncthreads();

    const float4* W4 = (const float4*)W;

    float muh[16], ph[16];
    float Ac = 0.0f;
    #pragma unroll
    for (int i = 0; i < 16; ++i) { muh[i] = 0.0f; ph[i] = 0.0f; }

    for (int iter = 0; iter < 3; ++iter) {
        // hoist per-c E-step constants from previous finalize
        if (iter > 0) {
            #pragma unroll
            for (int j = 0; j < 4; ++j) {
                float4 m4 = ((const float4*)&mu_s[c][0])[j];
                muh[j*4+0] = m4.x; muh[j*4+1] = m4.y; muh[j*4+2] = m4.z; muh[j*4+3] = m4.w;
                float4 p4 = ((const float4*)&p_s[c][0])[j];
                ph[j*4+0] = p4.x; ph[j*4+1] = p4.y; ph[j*4+2] = p4.z; ph[j*4+3] = p4.w;
            }
            Ac = A_s[c];
        }

        float S1[16], S2[16];
        #pragma unroll
        for (int i = 0; i < 16; ++i) { S1[i] = 0.0f; S2[i] = 0.0f; }
        float Racc = 0.0f;

        for (int s = 0; s < NSTEP; ++s) {
            const int n = wv * 72 + 2 * s + half;

            // load W[n][c][0..15] (coalesced: half-wave reads contiguous 2KB slice)
            float wreg[16], preg[16];
            {
                const float4* wp = W4 + (size_t)(n * 32 + c) * 4;
                float4 w0 = wp[0], w1 = wp[1], w2 = wp[2], w3 = wp[3];
                wreg[0]=w0.x; wreg[1]=w0.y; wreg[2]=w0.z; wreg[3]=w0.w;
                wreg[4]=w1.x; wreg[5]=w1.y; wreg[6]=w1.z; wreg[7]=w1.w;
                wreg[8]=w2.x; wreg[9]=w2.y; wreg[10]=w2.z; wreg[11]=w2.w;
                wreg[12]=w3.x; wreg[13]=w3.y; wreg[14]=w3.z; wreg[15]=w3.w;
                const float4* pp = (const float4*)&pose_s[n * 16];
                float4 p0 = pp[0], p1 = pp[1], p2 = pp[2], p3 = pp[3];
                preg[0]=p0.x; preg[1]=p0.y; preg[2]=p0.z; preg[3]=p0.w;
                preg[4]=p1.x; preg[5]=p1.y; preg[6]=p1.z; preg[7]=p1.w;
                preg[8]=p2.x; preg[9]=p2.y; preg[10]=p2.z; preg[11]=p2.w;
                preg[12]=p3.x; preg[13]=p3.y; preg[14]=p3.z; preg[15]=p3.w;
            }

            // v[i*4+l] = sum_j pose[i*4+j] * W[j*4+l]   (4x4 matmul)
            float v[16];
            #pragma unroll
            for (int i = 0; i < 4; ++i) {
                #pragma unroll
                for (int l = 0; l < 4; ++l) {
                    float acc = preg[i*4+0] * wreg[l];
                    acc = fmaf(preg[i*4+1], wreg[4 + l], acc);
                    acc = fmaf(preg[i*4+2], wreg[8 + l], acc);
                    acc = fmaf(preg[i*4+3], wreg[12 + l], acc);
                    v[i*4+l] = acc;
                }
            }

            float r;
            if (iter == 0) {
                r = ain_s[n] * 0.03125f;            // a_in / C
            } else {
                // ln_ap[n,c] = A_c - sum_il p*(v-mu)^2
                float acc = 0.0f;
                #pragma unroll
                for (int il = 0; il < 16; ++il) {
                    float d = v[il] - muh[il];
                    acc = fmaf(-ph[il], d * d, acc);
                }
                float lnap = Ac + acc;
                // softmax over the 32 lanes of this half-wave (axis c)
                float m = lnap;
                #pragma unroll
                for (int mk = 16; mk >= 1; mk >>= 1)
                    m = fmaxf(m, __shfl_xor(m, mk));
                float e = __expf(lnap - m);
                float ssum = e;
                #pragma unroll
                for (int mk = 16; mk >= 1; mk >>= 1)
                    ssum += __shfl_xor(ssum, mk);
                r = __fdividef(e, ssum);
            }

            Racc += r;
            #pragma unroll
            for (int il = 0; il < 16; ++il) {
                float rv = r * v[il];
                S1[il] += rv;
                S2[il] = fmaf(rv, v[il], S2[il]);
            }
        }

        // combine the two half-wave partials (same c, disjoint n)
        #pragma unroll
        for (int il = 0; il < 16; ++il) {
            S1[il] += __shfl_xor(S1[il], 32);
            S2[il] += __shfl_xor(S2[il], 32);
        }
        Racc += __shfl_xor(Racc, 32);

        if (half == 0) {
            #pragma unroll
            for (int il = 0; il < 16; ++il) {
                S1w[wv][c][il] = S1[il];
                S2w[wv][c][il] = S2[il];
            }
            Rw[wv][c] = Racc;
        }
        __syncthreads();

        // ---- finalize M-step: thread t = c2*8 + k handles il = k, k+8 ----
        {
            const int c2 = tid >> 3, k = tid & 7;
            float R = Rw[0][c2] + Rw[1][c2] + Rw[2][c2] + Rw[3][c2];
            float rinv = __fdividef(1.0f, R + 1e-8f);
            float muv[2], pv[2];
            float tpart = 0.0f;
            #pragma unroll
            for (int t2 = 0; t2 < 2; ++t2) {
                int il = k + t2 * 8;
                float s1 = S1w[0][c2][il] + S1w[1][c2][il] + S1w[2][c2][il] + S1w[3][c2][il];
                float s2 = S2w[0][c2][il] + S2w[1][c2][il] + S2w[2][c2][il] + S2w[3][c2][il];
                float mu  = s1 * rinv;
                float sig = fmaf(-mu, mu, s2 * rinv);
                sig = fmaxf(sig, 1e-30f);
                muv[t2] = mu;
                pv[t2]  = __fdividef(0.5f, sig);    // 1/(2*sigma^2)
                tpart  += __logf(sig);
            }
            #pragma unroll
            for (int mk = 4; mk >= 1; mk >>= 1)
                tpart += __shfl_xor(tpart, mk);      // sum_il log sigma^2 over 8 threads

            float cost = R * fmaf(0.5f, tpart, 16.0f * bu[c2]);
            float aout = __fdividef(1.0f, 1.0f + __expf(-(0.001f * (ba[c2] - cost))));

            if (iter < 2) {
                #pragma unroll
                for (int t2 = 0; t2 < 2; ++t2) {
                    int il = k + t2 * 8;
                    mu_s[c2][il] = muv[t2];
                    p_s[c2][il]  = pv[t2];
                }
                if (k == 0)
                    A_s[c2] = __logf(aout) - 0.5f * tpart - 8.0f * LN2PI;
            } else {
                #pragma unroll
                for (int t2 = 0; t2 < 2; ++t2) {
                    int il = k + t2 * 8;
                    out[(size_t)bid * 512 + c2 * 16 + il] = muv[t2];
                }
                if (k == 0)
                    out[294912 + bid * 32 + c2] = aout;
            }
        }
        __syncthreads();
    }
}

extern "C" void kernel_launch(void* const* d_in, const int* in_sizes, int n_in,
                              void* d_out, int out_size, void* d_ws, size_t ws_size,
                              hipStream_t stream) {
    (void)in_sizes; (void)n_in; (void)d_ws; (void)ws_size; (void)out_size;
    const float* x  = (const float*)d_in[0];
    const float* a  = (const float*)d_in[1];
    const float* w  = (const float*)d_in[2];
    const float* bu = (const float*)d_in[3];
    const float* ba = (const float*)d_in[4];
    float* out = (float*)d_out;
    hipLaunchKernelGGL(convcaps_em, dim3(576), dim3(256), 0, stream,
                       x, a, w, bu, ba, out);
}